// Round 3
// baseline (13.563 us; speedup 1.0000x reference)
//
#include <hip/hip_runtime.h>

#define NF 8
#define DEG 4
#define NTERMS 495
#define NPART 4        // term-ranges, one per wave
#define EPB 64         // elements per block

// ---------------------------------------------------------------------------
// Compile-time combinatorics: subtree at feature F with REM remaining degree
// covers C(NF-F+REM, REM) terms (lexicographic order, e0 slowest..e7 fastest,
// matching the reference meshgrid enumeration).
// ---------------------------------------------------------------------------
constexpr long long nCkll(int n, int k) {
    long long r = 1;
    for (int i = 1; i <= k; ++i) r = r * (n - k + i) / i;
    return r;
}
constexpr int subcnt(int F, int REM) { return (int)nCkll(NF - F + REM, REM); }

// ---------------------------------------------------------------------------
// Pruned prefix-product tree walk over term range [LO, HI).
// T0 = compile-time start index of this subtree. Leaves in-range emit
// a0 = fma(w[T0], p, a0) with a COMPILE-TIME LDS offset (consecutive in
// program order -> ds_read_b128 merging). Out-of-range subtrees prune to
// nothing (if constexpr); dead prefix muls are DCE'd.
// Accumulator pair swapped per branch step to break the serial FMA chain.
// ---------------------------------------------------------------------------
template<int F, int REM, int T0, int LO, int HI> struct Node;
template<int F, int REM, int E, int T0, int LO, int HI> struct Branch;

template<int F, int REM, int T0, int LO, int HI>
struct Node {
    static __device__ __forceinline__ void run(const float* xs, const float* w,
                                               float p, float& a0, float& a1) {
        if constexpr (T0 + subcnt(F, REM) <= LO || T0 >= HI) {
            (void)xs; (void)w; (void)p; (void)a0; (void)a1;   // pruned
        } else {
            Branch<F, REM, 0, T0, LO, HI>::run(xs, w, p, a0, a1);
        }
    }
};

// leaf: all 8 exponents assigned -> one term at compile-time index T0
template<int REM, int T0, int LO, int HI>
struct Node<NF, REM, T0, LO, HI> {
    static __device__ __forceinline__ void run(const float*, const float* w,
                                               float p, float& a0, float& a1) {
        (void)a1;
        if constexpr (T0 >= LO && T0 < HI) {
            a0 = fmaf(w[T0], p, a0);
        } else {
            (void)w; (void)p; (void)a0;
        }
    }
};

template<int F, int REM, int E, int T0, int LO, int HI>
struct Branch {
    static constexpr int childCnt = subcnt(F + 1, REM - E);
    static __device__ __forceinline__ void run(const float* xs, const float* w,
                                               float pf, float& a0, float& a1) {
        Node<F + 1, REM - E, T0, LO, HI>::run(xs, w, pf, a0, a1);
        if constexpr (E < REM) {
            Branch<F, REM, E + 1, T0 + childCnt, LO, HI>::run(xs, w, pf * xs[F], a1, a0);
        }
    }
};

// part boundaries: p*495/4 -> {0,123,247,371,495}
#define PB(p) ((p) * NTERMS / NPART)

__global__ __launch_bounds__(256)
void maclaurin_fused(const float* __restrict__ x,
                     const float* __restrict__ coefs,
                     const float* __restrict__ facs,
                     float* __restrict__ out, int n) {
    __shared__ __align__(16) float wl[NTERMS];
    __shared__ float partial[NPART][EPB];

    const int tid  = threadIdx.x;
    const int lane = tid & 63;          // element within block
    const int part = tid >> 6;          // wave id = term range (wave-uniform)
    const int elem = blockIdx.x * EPB + lane;

    // issue x loads first so their global latency hides under the LDS fill
    float xs[NF];
    if (elem < n) {
        const float4* xp = (const float4*)(x + (size_t)elem * NF);
        float4 v0 = xp[0];
        float4 v1 = xp[1];
        xs[0] = v0.x; xs[1] = v0.y; xs[2] = v0.z; xs[3] = v0.w;
        xs[4] = v1.x; xs[5] = v1.y; xs[6] = v1.z; xs[7] = v1.w;
    } else {
        #pragma unroll
        for (int f = 0; f < NF; ++f) xs[f] = 0.0f;
    }

    // per-block w = coefs * facs into LDS (495 floats)
    if (tid < NTERMS)       wl[tid]       = coefs[tid]       * facs[tid];
    if (tid + 256 < NTERMS) wl[tid + 256] = coefs[tid + 256] * facs[tid + 256];
    __syncthreads();

    float a0 = 0.0f, a1 = 0.0f;
    switch (part) {   // wave-uniform branch, one pruned tree per wave
        case 0: Node<0, DEG, 0, PB(0), PB(1)>::run(xs, wl, 1.0f, a0, a1); break;
        case 1: Node<0, DEG, 0, PB(1), PB(2)>::run(xs, wl, 1.0f, a0, a1); break;
        case 2: Node<0, DEG, 0, PB(2), PB(3)>::run(xs, wl, 1.0f, a0, a1); break;
        default:Node<0, DEG, 0, PB(3), PB(4)>::run(xs, wl, 1.0f, a0, a1); break;
    }
    partial[part][lane] = a0 + a1;
    __syncthreads();

    // reduce 4 partials, coalesced 64-float write per block
    if (tid < EPB) {
        int e = blockIdx.x * EPB + tid;
        if (e < n) {
            out[e] = (partial[0][tid] + partial[1][tid])
                   + (partial[2][tid] + partial[3][tid]);
        }
    }
}

// ---------------------------------------------------------------------------
// launch
// ---------------------------------------------------------------------------
extern "C" void kernel_launch(void* const* d_in, const int* in_sizes, int n_in,
                              void* d_out, int out_size, void* d_ws, size_t ws_size,
                              hipStream_t stream) {
    // inputs (setup_inputs order): x [B,8] f32, terms [495,8] f32,
    //                              coefs [1,495] f32, facs [495] f32
    const float* x     = (const float*)d_in[0];
    const float* coefs = (const float*)d_in[2];
    const float* facs  = (const float*)d_in[3];
    float* out = (float*)d_out;

    int n = in_sizes[0] / NF;           // 65536
    int grid = (n + EPB - 1) / EPB;     // 1024 blocks, 4 waves each

    maclaurin_fused<<<grid, 256, 0, stream>>>(x, coefs, facs, out, n);
}

// Round 4
// 9.661 us; speedup vs baseline: 1.4039x; 1.4039x over previous
//
#include <hip/hip_runtime.h>

#define NF 8
#define DEG 4
#define NTERMS 495

// ---------------------------------------------------------------------------
// Compile-time combinatorics: subtree at feature F with REM remaining degree
// covers C(NF-F+REM, REM) terms (lexicographic order, e0 slowest..e7 fastest,
// matching the reference meshgrid enumeration).
// ---------------------------------------------------------------------------
constexpr long long nCkll(int n, int k) {
    long long r = 1;
    for (int i = 1; i <= k; ++i) r = r * (n - k + i) / i;
    return r;
}
constexpr int subcnt(int F, int REM) { return (int)nCkll(NF - F + REM, REM); }

// ---------------------------------------------------------------------------
// Prefix-product tree walk, terms consumed strictly sequentially (T0 is the
// compile-time term index). w is read from LDS as float4 quads: the leaf with
// T0%4==0 loads quad T0/4 (ds_read_b128, compile-time offset); the next 3
// leaves consume its lanes. Accumulator acc[T0&3] -> 4 independent FMA
// chains. All indices constant-fold (no scratch, rule #20 safe).
// ---------------------------------------------------------------------------
template<int F, int REM, int T0> struct Node;
template<int F, int REM, int E, int T0> struct Branch;

template<int F, int REM, int T0>
struct Node {
    static __device__ __forceinline__ void run(const float* xs, const float4* w4,
                                               float4& wq, float p, float* acc) {
        Branch<F, REM, 0, T0>::run(xs, w4, wq, p, acc);
    }
};

// leaf: one term at compile-time index T0
template<int REM, int T0>
struct Node<NF, REM, T0> {
    static __device__ __forceinline__ void run(const float*, const float4* w4,
                                               float4& wq, float p, float* acc) {
        if constexpr ((T0 & 3) == 0) {
            wq = w4[T0 / 4];            // ds_read_b128, imm offset
        }
        constexpr int c = T0 & 3;
        float wv = (c == 0) ? wq.x : (c == 1) ? wq.y : (c == 2) ? wq.z : wq.w;
        acc[c] = fmaf(wv, p, acc[c]);
    }
};

template<int F, int REM, int E, int T0>
struct Branch {
    static constexpr int childCnt = subcnt(F + 1, REM - E);
    static __device__ __forceinline__ void run(const float* xs, const float4* w4,
                                               float4& wq, float pf, float* acc) {
        Node<F + 1, REM - E, T0>::run(xs, w4, wq, pf, acc);
        if constexpr (E < REM) {
            Branch<F, REM, E + 1, T0 + childCnt>::run(xs, w4, wq, pf * xs[F], acc);
        }
    }
};

__global__ __launch_bounds__(256)
void maclaurin_fused(const float* __restrict__ x,
                     const float* __restrict__ coefs,
                     const float* __restrict__ facs,
                     float* __restrict__ out, int n) {
    __shared__ __align__(16) float wl[496];   // padded to full quads

    const int tid = threadIdx.x;
    const int b   = blockIdx.x * blockDim.x + tid;

    // issue x loads first so their global latency hides under the LDS fill
    float xs[NF];
    if (b < n) {
        const float4* xp = (const float4*)(x + (size_t)b * NF);
        float4 v0 = xp[0];
        float4 v1 = xp[1];
        xs[0] = v0.x; xs[1] = v0.y; xs[2] = v0.z; xs[3] = v0.w;
        xs[4] = v1.x; xs[5] = v1.y; xs[6] = v1.z; xs[7] = v1.w;
    }

    // vectorized per-block fill: w = coefs * facs (495 floats, 123 quads + 3)
    if (tid < 123) {
        float4 c = ((const float4*)coefs)[tid];
        float4 f = ((const float4*)facs)[tid];
        ((float4*)wl)[tid] = make_float4(c.x * f.x, c.y * f.y, c.z * f.z, c.w * f.w);
    } else if (tid < 126) {
        int i = 492 + (tid - 123);
        wl[i] = coefs[i] * facs[i];
    } else if (tid == 126) {
        wl[495] = 0.0f;                 // pad lane (read by quad 123, never used)
    }
    __syncthreads();

    if (b >= n) return;

    float acc[4] = {0.0f, 0.0f, 0.0f, 0.0f};
    float4 wq;
    Node<0, DEG, 0>::run(xs, (const float4*)wl, wq, 1.0f, acc);

    out[b] = (acc[0] + acc[1]) + (acc[2] + acc[3]);
}

// ---------------------------------------------------------------------------
// launch
// ---------------------------------------------------------------------------
extern "C" void kernel_launch(void* const* d_in, const int* in_sizes, int n_in,
                              void* d_out, int out_size, void* d_ws, size_t ws_size,
                              hipStream_t stream) {
    // inputs (setup_inputs order): x [B,8] f32, terms [495,8] f32,
    //                              coefs [1,495] f32, facs [495] f32
    const float* x     = (const float*)d_in[0];
    const float* coefs = (const float*)d_in[2];
    const float* facs  = (const float*)d_in[3];
    float* out = (float*)d_out;

    int n = in_sizes[0] / NF;    // 65536

    maclaurin_fused<<<(n + 255) / 256, 256, 0, stream>>>(x, coefs, facs, out, n);
}

// Round 5
// 9.401 us; speedup vs baseline: 1.4427x; 1.0277x over previous
//
#include <hip/hip_runtime.h>

#define NF 8
#define DEG 4
#define NTERMS 495

// ---------------------------------------------------------------------------
// Compile-time combinatorics: sub-polynomial over vars x_F..x_{NF-1} with
// total degree <= REM has subcnt(F,REM) = C(NF-F+REM, REM) coefficients
// (lexicographic order, e0 slowest..e7 fastest, matching the reference
// meshgrid enumeration -- verified by the passing R2/R4 kernels).
// ---------------------------------------------------------------------------
constexpr long long nCkll(int n, int k) {
    long long r = 1;
    for (int i = 1; i <= k; ++i) r = r * (n - k + i) / i;
    return r;
}
constexpr int subcnt(int F, int REM) { return (int)nCkll(NF - F + REM, REM); }

// start offset (within the node's coefficient range) of child e:
// children j=0..e-1 precede it, child j covers subcnt(F+1, REM-j) terms
constexpr int csum(int F, int REM, int E) {
    int s = 0;
    for (int j = 0; j < E; ++j) s += subcnt(F + 1, REM - j);
    return s;
}

// ---------------------------------------------------------------------------
// Full multivariate Horner: P(x_F..x_7) = (((c_REM)*x_F + c_{REM-1})*x_F + ...
// )*x_F + c_0, where each c_e is itself a Horner-evaluated sub-polynomial in
// x_{F+1}..x_7. Touches each of the 495 coefficients exactly ONCE ->
// 494 FMAs total (vs 1286 mul + 495 fma for the monomial tree).
// Descending-e evaluation consumes term indices in exact reverse-sequential
// order, so w is read from LDS as float4 quads loaded when first touched
// (T0&3==3 or T0==494) and consumed lanes w,z,y,x. All indices constant-fold.
// ---------------------------------------------------------------------------
template<int F, int REM, int T0> struct HNode;
template<int F, int REM, int E, int T0> struct HChain;

template<int F, int REM, int T0>
struct HNode {
    static __device__ __forceinline__ float eval(const float* xs, const float4* w4,
                                                 float4& wq) {
        // child e=REM (single coefficient: all remaining degree spent on x_F)
        float acc = HNode<F + 1, 0, T0 + csum(F, REM, REM)>::eval(xs, w4, wq);
        if constexpr (REM > 0)
            acc = HChain<F, REM, REM - 1, T0>::step(acc, xs, w4, wq);
        return acc;
    }
};

// leaf: single coefficient at compile-time term index T0
template<int REM, int T0>
struct HNode<NF, REM, T0> {
    static __device__ __forceinline__ float eval(const float*, const float4* w4,
                                                 float4& wq) {
        if constexpr ((T0 & 3) == 3 || T0 == NTERMS - 1)
            wq = w4[T0 >> 2];          // ds_read_b128, imm offset
        constexpr int c = T0 & 3;
        return (c == 0) ? wq.x : (c == 1) ? wq.y : (c == 2) ? wq.z : wq.w;
    }
};

template<int F, int REM, int E, int T0>
struct HChain {
    static __device__ __forceinline__ float step(float acc, const float* xs,
                                                 const float4* w4, float4& wq) {
        float c = HNode<F + 1, REM - E, T0 + csum(F, REM, E)>::eval(xs, w4, wq);
        acc = fmaf(acc, xs[F], c);
        if constexpr (E > 0)
            return HChain<F, REM, E - 1, T0>::step(acc, xs, w4, wq);
        else
            return acc;
    }
};

__global__ __launch_bounds__(256)
void maclaurin_fused(const float* __restrict__ x,
                     const float* __restrict__ coefs,
                     const float* __restrict__ facs,
                     float* __restrict__ out, int n) {
    __shared__ __align__(16) float wl[496];   // padded to full quads

    const int tid = threadIdx.x;
    const int b   = blockIdx.x * blockDim.x + tid;

    // issue x loads first so their global latency hides under the LDS fill
    float xs[NF];
    if (b < n) {
        const float4* xp = (const float4*)(x + (size_t)b * NF);
        float4 v0 = xp[0];
        float4 v1 = xp[1];
        xs[0] = v0.x; xs[1] = v0.y; xs[2] = v0.z; xs[3] = v0.w;
        xs[4] = v1.x; xs[5] = v1.y; xs[6] = v1.z; xs[7] = v1.w;
    }

    // vectorized per-block fill: w = coefs * facs (495 floats, 123 quads + 3)
    if (tid < 123) {
        float4 c = ((const float4*)coefs)[tid];
        float4 f = ((const float4*)facs)[tid];
        ((float4*)wl)[tid] = make_float4(c.x * f.x, c.y * f.y, c.z * f.z, c.w * f.w);
    } else if (tid < 126) {
        int i = 492 + (tid - 123);
        wl[i] = coefs[i] * facs[i];
    } else if (tid == 126) {
        wl[495] = 0.0f;                 // pad lane (read by quad 123, never used)
    }
    __syncthreads();

    if (b >= n) return;

    float4 wq;
    float r = HNode<0, DEG, 0>::eval(xs, (const float4*)wl, wq);

    out[b] = r;
}

// ---------------------------------------------------------------------------
// launch
// ---------------------------------------------------------------------------
extern "C" void kernel_launch(void* const* d_in, const int* in_sizes, int n_in,
                              void* d_out, int out_size, void* d_ws, size_t ws_size,
                              hipStream_t stream) {
    // inputs (setup_inputs order): x [B,8] f32, terms [495,8] f32,
    //                              coefs [1,495] f32, facs [495] f32
    const float* x     = (const float*)d_in[0];
    const float* coefs = (const float*)d_in[2];
    const float* facs  = (const float*)d_in[3];
    float* out = (float*)d_out;

    int n = in_sizes[0] / NF;    // 65536

    maclaurin_fused<<<(n + 255) / 256, 256, 0, stream>>>(x, coefs, facs, out, n);
}